// Round 15
// baseline (1812.862 us; speedup 1.0000x reference)
//
#include <hip/hip_runtime.h>

// Problem constants (B=2, N=8192, C=64, K=32 neighbors). All device buffers fp32.
static constexpr int gB = 2;
static constexpr int gN = 8192;
static constexpr int gC = 64;
static constexpr int gK = 32;

using u32 = unsigned int;
using u64 = unsigned long long;

// wave(64)-wide sum
__device__ __forceinline__ float wsum(float v) {
#pragma unroll
    for (int m = 32; m; m >>= 1) v += __shfl_xor(v, m, 64);
    return v;
}

// =====================================================================
// A: fn = LN1(features); Q/K/V = fn@W+b.  Wave-per-point. (unchanged)
// =====================================================================
__global__ __launch_bounds__(256) void k_lnqkv(
    const float* __restrict__ feat, const float* __restrict__ ln1g, const float* __restrict__ ln1b,
    const float* __restrict__ Wq, const float* __restrict__ bq,
    const float* __restrict__ Wk, const float* __restrict__ bk,
    const float* __restrict__ Wv, const float* __restrict__ bv,
    float* __restrict__ Qo, float* __restrict__ Ko, float* __restrict__ Vo,
    float* __restrict__ zero_region)
{
    if (blockIdx.x == 0) zero_region[threadIdx.x] = 0.f;   // meanb(128)+cw(128)
    int wave = threadIdx.x >> 6, lane = threadIdx.x & 63;
    int p = blockIdx.x * 4 + wave;
    float x = feat[(size_t)p * gC + lane];
    float mu = wsum(x) * (1.f / 64);
    float d = x - mu;
    float var = wsum(d * d) * (1.f / 64);
    float inv = 1.f / sqrtf(var + 1e-5f);
    float fn = d * inv * ln1g[lane] + ln1b[lane];
    float qa = bq[lane], ka = bk[lane], va = bv[lane];
    for (int cp = 0; cp < 64; ++cp) {
        float hv = __shfl(fn, cp, 64);
        qa += hv * Wq[cp * 64 + lane];
        ka += hv * Wk[cp * 64 + lane];
        va += hv * Wv[cp * 64 + lane];
    }
    size_t o = (size_t)p * gC + lane;
    Qo[o] = qa; Ko[o] = ka; Vo[o] = va;
}

// =====================================================================
// B: KNN top-32 — wave-per-query, register top-10 per lane. (unchanged)
// =====================================================================
__global__ __launch_bounds__(64) void k_knn(const float* __restrict__ xyz, int* __restrict__ idxo)
{
#pragma clang fp contract(off)
    int lane = threadIdx.x;
    int q = blockIdx.x;               // 0..16383
    int b = q >> 13;
    int n = q & (gN - 1);
    const float* base = xyz + (size_t)b * gN * 3;
    float xi = base[n * 3 + 0];
    float yi = base[n * 3 + 1];
    float zi = base[n * 3 + 2];
    float ni_ = sqrtf((xi * xi + yi * yi) + zi * zi);
    float sqi = ni_ * ni_;                        // norm-then-square
    u64 lst[10];
#pragma unroll
    for (int e = 0; e < 10; ++e) lst[e] = 0ull;
    for (int jj = 0; jj < 128; ++jj) {
        int j = (jj << 6) | lane;
        float x = base[j * 3 + 0];
        float y = base[j * 3 + 1];
        float z = base[j * 3 + 2];
        float nj_ = sqrtf((x * x + y * y) + z * z);
        float sqj = nj_ * nj_;                    // norm-then-square
        float inner = (xi * x + yi * y) + zi * z;
        float nd = -((sqi - 2.0f * inner) + sqj);
        u32 u = __float_as_uint(nd);
        u32 kh = u ^ (0x80000000u | (u32)((int)u >> 31));   // order-preserving
        u64 pk = ((u64)kh << 32) | (u32)(8191 - j);          // ties -> smaller j
        if (pk > lst[9]) {
            lst[9] = pk;
#pragma unroll
            for (int e = 9; e > 0; --e) {
                if (lst[e] > lst[e - 1]) { u64 t = lst[e - 1]; lst[e - 1] = lst[e]; lst[e] = t; }
            }
        }
    }
    int* op = idxo + (size_t)q * gK;
    for (int r = 0; r < gK; ++r) {
        u64 g = lst[0];
#pragma unroll
        for (int m = 32; m; m >>= 1) {
            u64 o = __shfl_xor(g, m, 64);
            g = (o > g) ? o : g;
        }
        if (lst[0] == g) {                        // unique owner pops
#pragma unroll
            for (int e = 0; e < 9; ++e) lst[e] = lst[e + 1];
            lst[9] = 0ull;
        }
        if (lane == 0) op[r] = 8191 - (int)(g & 0x1FFFu);
    }
}

// =====================================================================
// C: R15 — lanes-as-neighbors, ALL-REGISTER MLP chain (no activation
// LDS). Wave = 2 points x 32 neighbors; each lane's chain is lane-local
// in 3 fully-unrolled register arrays (pe in acc, h, g). Weights are
// wave-uniform scalar loads. Arithmetic order identical to the R14
// passing kernel. LDS = 512 B (q broadcast). launch_bounds(64,2) pins
// <=256 VGPR -> 2 waves/SIMD.
// =====================================================================
__global__ __launch_bounds__(64, 2) void k_attn(
    const float* __restrict__ xyz,
    const float* __restrict__ Qb, const float* __restrict__ Kb, const float* __restrict__ Vb,
    const int* __restrict__ idxi,
    const float* __restrict__ dW1, const float* __restrict__ db1,
    const float* __restrict__ dgv, const float* __restrict__ dbv,
    const float* __restrict__ dW2, const float* __restrict__ db2,
    const float* __restrict__ gW1, const float* __restrict__ gb1,
    const float* __restrict__ ggv, const float* __restrict__ gbv,
    const float* __restrict__ gW2, const float* __restrict__ gb2,
    float* __restrict__ att)
{
    __shared__ float qlds[2][64];
    int lane = threadIdx.x;
    int half = lane >> 5;
    int kk = lane & 31;
    int pA = blockIdx.x * 2;
    int p = pA + half;
    int b = p >> 13;

    qlds[0][lane] = Qb[(size_t)pA * gC + lane];
    qlds[1][lane] = Qb[(size_t)(pA + 1) * gC + lane];
    __syncthreads();

    int j = idxi[(size_t)p * gK + kk];
    const float* xp = xyz + (size_t)p * 3;
    const float* xj = xyz + ((size_t)b * gN + j) * 3;
    float dx = xp[0] - xj[0];
    float dy = xp[1] - xj[1];
    float dz = xp[2] - xj[2];

    float acc[64], h[64], g[64];

    // ---- fc_delta layer 1 ----
#pragma unroll
    for (int c = 0; c < 64; ++c)
        acc[c] = dx * dW1[c] + dy * dW1[64 + c] + dz * dW1[128 + c] + db1[c];

    // ---- LN (in-lane) + relu -> h ----
    {
        float s0 = 0, s1 = 0, s2 = 0, s3 = 0;
#pragma unroll
        for (int c = 0; c < 64; c += 4) { s0 += acc[c]; s1 += acc[c + 1]; s2 += acc[c + 2]; s3 += acc[c + 3]; }
        float mu = ((s0 + s1) + (s2 + s3)) * (1.f / 64);
        float v0 = 0, v1 = 0, v2 = 0, v3 = 0;
#pragma unroll
        for (int c = 0; c < 64; c += 4) {
            acc[c] -= mu; acc[c + 1] -= mu; acc[c + 2] -= mu; acc[c + 3] -= mu;
            v0 += acc[c] * acc[c]; v1 += acc[c + 1] * acc[c + 1];
            v2 += acc[c + 2] * acc[c + 2]; v3 += acc[c + 3] * acc[c + 3];
        }
        float var = ((v0 + v1) + (v2 + v3)) * (1.f / 64);
        float inv = 1.f / sqrtf(var + 1e-5f);
#pragma unroll
        for (int c = 0; c < 64; ++c)
            h[c] = fmaxf(acc[c] * inv * dgv[c] + dbv[c], 0.f);
    }

    // ---- fc_delta layer 2: pe = h @ dW2 + db2 -> acc (stays live) ----
#pragma unroll
    for (int c = 0; c < 64; ++c) acc[c] = db2[c];
#pragma unroll
    for (int cp = 0; cp < 64; ++cp) {
        float hv = h[cp];
#pragma unroll
        for (int c = 0; c < 64; ++c) acc[c] += hv * dW2[cp * 64 + c];
    }

    // ---- attn_in = (q - k) + pe -> h ----
    {
        const float* Kj = Kb + ((size_t)b * gN + j) * gC;
#pragma unroll
        for (int c4 = 0; c4 < 16; ++c4) {
            float4 kv = reinterpret_cast<const float4*>(Kj)[c4];
            int c = c4 * 4;
            h[c + 0] = (qlds[half][c + 0] - kv.x) + acc[c + 0];
            h[c + 1] = (qlds[half][c + 1] - kv.y) + acc[c + 1];
            h[c + 2] = (qlds[half][c + 2] - kv.z) + acc[c + 2];
            h[c + 3] = (qlds[half][c + 3] - kv.w) + acc[c + 3];
        }
    }

    // ---- fc_gamma layer 1 -> g ----
#pragma unroll
    for (int c = 0; c < 64; ++c) g[c] = gb1[c];
#pragma unroll
    for (int cp = 0; cp < 64; ++cp) {
        float hv = h[cp];
#pragma unroll
        for (int c = 0; c < 64; ++c) g[c] += hv * gW1[cp * 64 + c];
    }

    // ---- LN + relu -> h ----
    {
        float s0 = 0, s1 = 0, s2 = 0, s3 = 0;
#pragma unroll
        for (int c = 0; c < 64; c += 4) { s0 += g[c]; s1 += g[c + 1]; s2 += g[c + 2]; s3 += g[c + 3]; }
        float mu = ((s0 + s1) + (s2 + s3)) * (1.f / 64);
        float v0 = 0, v1 = 0, v2 = 0, v3 = 0;
#pragma unroll
        for (int c = 0; c < 64; c += 4) {
            g[c] -= mu; g[c + 1] -= mu; g[c + 2] -= mu; g[c + 3] -= mu;
            v0 += g[c] * g[c]; v1 += g[c + 1] * g[c + 1];
            v2 += g[c + 2] * g[c + 2]; v3 += g[c + 3] * g[c + 3];
        }
        float var = ((v0 + v1) + (v2 + v3)) * (1.f / 64);
        float inv = 1.f / sqrtf(var + 1e-5f);
#pragma unroll
        for (int c = 0; c < 64; ++c)
            h[c] = fmaxf(g[c] * inv * ggv[c] + gbv[c], 0.f);
    }

    // ---- fc_gamma layer 2 -> g (logits after scale) ----
#pragma unroll
    for (int c = 0; c < 64; ++c) g[c] = gb2[c];
#pragma unroll
    for (int cp = 0; cp < 64; ++cp) {
        float hv = h[cp];
#pragma unroll
        for (int c = 0; c < 64; ++c) g[c] += hv * gW2[cp * 64 + c];
    }
#pragma unroll
    for (int c = 0; c < 64; ++c)
        g[c] = g[c] * 0.3535533905932738f;       // /sqrt(8)

    // ---- per-channel softmax over k (half-wave) + out = sum a*(v+pe) ----
    {
        const float* Vj = Vb + ((size_t)b * gN + j) * gC;
        float* op = att + (size_t)p * gC;
#pragma unroll
        for (int c4 = 0; c4 < 16; ++c4) {
            float4 vv4 = reinterpret_cast<const float4*>(Vj)[c4];
            float vva[4] = {vv4.x, vv4.y, vv4.z, vv4.w};
#pragma unroll
            for (int i = 0; i < 4; ++i) {
                int c = c4 * 4 + i;
                float l = g[c];
                float gm = l;
#pragma unroll
                for (int m = 16; m; m >>= 1) gm = fmaxf(gm, __shfl_xor(gm, m, 64));
                float e = expf(l - gm);
                float w = e * (vva[i] + acc[c]);   // acc = pe
                float se = e, sw = w;
#pragma unroll
                for (int m = 16; m; m >>= 1) {
                    se += __shfl_xor(se, m, 64);
                    sw += __shfl_xor(sw, m, 64);
                }
                if (kk == (c & 31)) op[c] = sw / se;
            }
        }
    }
}

// =====================================================================
// D: out2 = LN2(att @ Wo + bo) in place; accumulate channel mean. (unchanged)
// =====================================================================
__global__ __launch_bounds__(256) void k_out(
    float* __restrict__ att,
    const float* __restrict__ Wo, const float* __restrict__ bo,
    const float* __restrict__ ln2g, const float* __restrict__ ln2b,
    float* __restrict__ meanb)
{
    __shared__ __align__(16) float hb[4][64];
    int lane = threadIdx.x & 63;
    int p = blockIdx.x * 4 + (threadIdx.x >> 6);
    int b = p >> 13;
    float* hbuf = hb[threadIdx.x >> 6];
    float wo[64];
#pragma unroll
    for (int r = 0; r < 64; ++r) wo[r] = Wo[r * 64 + lane];
    float x = att[(size_t)p * gC + lane];
    hbuf[lane] = x;
    float acc = bo[lane];
#pragma unroll
    for (int q4 = 0; q4 < 16; ++q4) {
        float4 hq = *reinterpret_cast<const float4*>(&hbuf[q4 * 4]);
        acc += hq.x * wo[q4 * 4 + 0] + hq.y * wo[q4 * 4 + 1]
             + hq.z * wo[q4 * 4 + 2] + hq.w * wo[q4 * 4 + 3];
    }
    float mu = wsum(acc) * (1.f / 64);
    float d = acc - mu;
    float var = wsum(d * d) * (1.f / 64);
    float inv = 1.f / sqrtf(var + 1e-5f);
    float y = d * inv * ln2g[lane] + ln2b[lane];
    att[(size_t)p * gC + lane] = y;
    atomicAdd(&meanb[b * 64 + lane], y * (1.f / gN));
}

// =====================================================================
// E: cw = sigmoid(relu(mean @ ca_W1 + ca_b1) @ ca_W2 + ca_b2) (unchanged)
// =====================================================================
__global__ void k_cw(const float* __restrict__ meanb,
                     const float* __restrict__ caW1, const float* __restrict__ cab1,
                     const float* __restrict__ caW2, const float* __restrict__ cab2,
                     float* __restrict__ cw)
{
    int b = blockIdx.x, lane = threadIdx.x;    // 64 threads
    float mv = meanb[b * 64 + lane];
    float hj = (lane < 16) ? cab1[lane] : 0.f;
    for (int cp = 0; cp < 64; ++cp) {
        float mcp = __shfl(mv, cp, 64);
        if (lane < 16) hj += mcp * caW1[cp * 16 + lane];
    }
    hj = fmaxf(hj, 0.f);
    float acc = cab2[lane];
    for (int jj = 0; jj < 16; ++jj) {
        float hv = __shfl(hj, jj, 64);
        acc += hv * caW2[jj * 64 + lane];
    }
    cw[b * 64 + lane] = 1.f / (1.f + expf(-acc));
}

// =====================================================================
// F: out = LN3(out2 * cw) + features  -> fp32 (unchanged)
// =====================================================================
__global__ __launch_bounds__(256) void k_final(
    const float* __restrict__ out2, const float* __restrict__ cw,
    const float* __restrict__ ln3g, const float* __restrict__ ln3b,
    const float* __restrict__ feat, float* __restrict__ outp)
{
    int lane = threadIdx.x & 63;
    int p = blockIdx.x * 4 + (threadIdx.x >> 6);
    int b = p >> 13;
    float x = out2[(size_t)p * gC + lane] * cw[b * 64 + lane];
    float mu = wsum(x) * (1.f / 64);
    float d = x - mu;
    float var = wsum(d * d) * (1.f / 64);
    float inv = 1.f / sqrtf(var + 1e-5f);
    float y = d * inv * ln3g[lane] + ln3b[lane];
    outp[(size_t)p * gC + lane] = y + feat[(size_t)p * gC + lane];
}

// =====================================================================
extern "C" void kernel_launch(void* const* d_in, const int* in_sizes, int n_in,
                              void* d_out, int out_size, void* d_ws, size_t ws_size,
                              hipStream_t stream)
{
    (void)in_sizes; (void)n_in; (void)out_size; (void)ws_size;
    const float* xyz  = (const float*)d_in[0];
    const float* feat = (const float*)d_in[1];
    const float* ln1g = (const float*)d_in[2];
    const float* ln1b = (const float*)d_in[3];
    const float* Wq   = (const float*)d_in[4];
    const float* bq   = (const float*)d_in[5];
    const float* Wk   = (const float*)d_in[6];
    const float* bk   = (const float*)d_in[7];
    const float* Wv   = (const float*)d_in[8];
    const float* bv   = (const float*)d_in[9];
    const float* dW1  = (const float*)d_in[10];
    const float* db1  = (const float*)d_in[11];
    const float* dg   = (const float*)d_in[12];
    const float* db   = (const float*)d_in[13];
    const float* dW2  = (const float*)d_in[14];
    const float* db2  = (const float*)d_in[15];
    const float* gW1  = (const float*)d_in[16];
    const float* gb1  = (const float*)d_in[17];
    const float* gg   = (const float*)d_in[18];
    const float* gb   = (const float*)d_in[19];
    const float* gW2  = (const float*)d_in[20];
    const float* gb2  = (const float*)d_in[21];
    const float* Wo   = (const float*)d_in[22];
    const float* bo   = (const float*)d_in[23];
    const float* ln2g = (const float*)d_in[24];
    const float* ln2b = (const float*)d_in[25];
    const float* caW1 = (const float*)d_in[26];
    const float* cab1 = (const float*)d_in[27];
    const float* caW2 = (const float*)d_in[28];
    const float* cab2 = (const float*)d_in[29];
    const float* ln3g = (const float*)d_in[30];
    const float* ln3b = (const float*)d_in[31];

    const size_t BNC = (size_t)gB * gN * gC;      // 1,048,576
    float* Q    = (float*)d_ws;
    float* Kt   = Q + BNC;
    float* Vt   = Kt + BNC;
    float* att  = Vt + BNC;                        // reused in-place as out2
    int*   idx  = (int*)(att + BNC);
    float* meanb = (float*)(idx + (size_t)gB * gN * gK);
    float* cw    = meanb + 128;

    const int PB = (gB * gN) / 4;                  // 4096 blocks, wave-per-point

    k_lnqkv<<<PB, 256, 0, stream>>>(feat, ln1g, ln1b, Wq, bq, Wk, bk, Wv, bv, Q, Kt, Vt, meanb);
    k_knn<<<gB * gN, 64, 0, stream>>>(xyz, idx);
    k_attn<<<(gB * gN) / 2, 64, 0, stream>>>(xyz, Q, Kt, Vt, idx,
                                             dW1, db1, dg, db, dW2, db2,
                                             gW1, gb1, gg, gb, gW2, gb2, att);
    k_out<<<PB, 256, 0, stream>>>(att, Wo, bo, ln2g, ln2b, meanb);
    k_cw<<<gB, 64, 0, stream>>>(meanb, caW1, cab1, caW2, cab2, cw);
    k_final<<<PB, 256, 0, stream>>>(att, cw, ln3g, ln3b, feat, (float*)d_out);
}

// Round 16
// 1120.325 us; speedup vs baseline: 1.6182x; 1.6182x over previous
//
#include <hip/hip_runtime.h>

// Problem constants (B=2, N=8192, C=64, K=32 neighbors). All device buffers fp32.
static constexpr int gB = 2;
static constexpr int gN = 8192;
static constexpr int gC = 64;
static constexpr int gK = 32;

using u32 = unsigned int;
using u64 = unsigned long long;

// wave(64)-wide sum
__device__ __forceinline__ float wsum(float v) {
#pragma unroll
    for (int m = 32; m; m >>= 1) v += __shfl_xor(v, m, 64);
    return v;
}

// =====================================================================
// A: fn = LN1(features); Q/K/V = fn@W+b.  Wave-per-point. (unchanged)
// =====================================================================
__global__ __launch_bounds__(256) void k_lnqkv(
    const float* __restrict__ feat, const float* __restrict__ ln1g, const float* __restrict__ ln1b,
    const float* __restrict__ Wq, const float* __restrict__ bq,
    const float* __restrict__ Wk, const float* __restrict__ bk,
    const float* __restrict__ Wv, const float* __restrict__ bv,
    float* __restrict__ Qo, float* __restrict__ Ko, float* __restrict__ Vo,
    float* __restrict__ zero_region)
{
    if (blockIdx.x == 0) zero_region[threadIdx.x] = 0.f;   // meanb(128)+cw(128)
    int wave = threadIdx.x >> 6, lane = threadIdx.x & 63;
    int p = blockIdx.x * 4 + wave;
    float x = feat[(size_t)p * gC + lane];
    float mu = wsum(x) * (1.f / 64);
    float d = x - mu;
    float var = wsum(d * d) * (1.f / 64);
    float inv = 1.f / sqrtf(var + 1e-5f);
    float fn = d * inv * ln1g[lane] + ln1b[lane];
    float qa = bq[lane], ka = bk[lane], va = bv[lane];
    for (int cp = 0; cp < 64; ++cp) {
        float hv = __shfl(fn, cp, 64);
        qa += hv * Wq[cp * 64 + lane];
        ka += hv * Wk[cp * 64 + lane];
        va += hv * Wv[cp * 64 + lane];
    }
    size_t o = (size_t)p * gC + lane;
    Qo[o] = qa; Ko[o] = ka; Vo[o] = va;
}

// =====================================================================
// B: KNN top-32 — wave-per-query, register top-10 per lane. (unchanged)
// =====================================================================
__global__ __launch_bounds__(64) void k_knn(const float* __restrict__ xyz, int* __restrict__ idxo)
{
#pragma clang fp contract(off)
    int lane = threadIdx.x;
    int q = blockIdx.x;               // 0..16383
    int b = q >> 13;
    int n = q & (gN - 1);
    const float* base = xyz + (size_t)b * gN * 3;
    float xi = base[n * 3 + 0];
    float yi = base[n * 3 + 1];
    float zi = base[n * 3 + 2];
    float ni_ = sqrtf((xi * xi + yi * yi) + zi * zi);
    float sqi = ni_ * ni_;                        // norm-then-square
    u64 lst[10];
#pragma unroll
    for (int e = 0; e < 10; ++e) lst[e] = 0ull;
    for (int jj = 0; jj < 128; ++jj) {
        int j = (jj << 6) | lane;
        float x = base[j * 3 + 0];
        float y = base[j * 3 + 1];
        float z = base[j * 3 + 2];
        float nj_ = sqrtf((x * x + y * y) + z * z);
        float sqj = nj_ * nj_;                    // norm-then-square
        float inner = (xi * x + yi * y) + zi * z;
        float nd = -((sqi - 2.0f * inner) + sqj);
        u32 u = __float_as_uint(nd);
        u32 kh = u ^ (0x80000000u | (u32)((int)u >> 31));   // order-preserving
        u64 pk = ((u64)kh << 32) | (u32)(8191 - j);          // ties -> smaller j
        if (pk > lst[9]) {
            lst[9] = pk;
#pragma unroll
            for (int e = 9; e > 0; --e) {
                if (lst[e] > lst[e - 1]) { u64 t = lst[e - 1]; lst[e - 1] = lst[e]; lst[e] = t; }
            }
        }
    }
    int* op = idxo + (size_t)q * gK;
    for (int r = 0; r < gK; ++r) {
        u64 g = lst[0];
#pragma unroll
        for (int m = 32; m; m >>= 1) {
            u64 o = __shfl_xor(g, m, 64);
            g = (o > g) ? o : g;
        }
        if (lst[0] == g) {                        // unique owner pops
#pragma unroll
            for (int e = 0; e < 9; ++e) lst[e] = lst[e + 1];
            lst[9] = 0ull;
        }
        if (lane == 0) op[r] = 8191 - (int)(g & 0x1FFFu);
    }
}

// =====================================================================
// C: R16 — R14 structure with peb LDS replaced by a pe register array.
// Wave = 2 points x 32 neighbors. ONE LDS activation buffer (actb,
// 16 KB) + TWO 64-float register arrays (acc for matmul accumulation —
// proven in R14 at VGPR=132 — and pe). LDS 33.3 -> 16.9 KB => 9
// blocks/CU. Arithmetic order bit-identical to the R14 passing kernel.
// =====================================================================
__global__ __launch_bounds__(64, 2) void k_attn(
    const float* __restrict__ xyz,
    const float* __restrict__ Qb, const float* __restrict__ Kb, const float* __restrict__ Vb,
    const int* __restrict__ idxi,
    const float* __restrict__ dW1, const float* __restrict__ db1,
    const float* __restrict__ dgv, const float* __restrict__ dbv,
    const float* __restrict__ dW2, const float* __restrict__ db2,
    const float* __restrict__ gW1, const float* __restrict__ gb1,
    const float* __restrict__ ggv, const float* __restrict__ gbv,
    const float* __restrict__ gW2, const float* __restrict__ gb2,
    float* __restrict__ att)
{
    __shared__ float actb[64][64];   // [c][lane] activation columns
    __shared__ float qlds[2][64];
    int lane = threadIdx.x;
    int half = lane >> 5;
    int kk = lane & 31;
    int pA = blockIdx.x * 2;
    int p = pA + half;
    int b = p >> 13;

    qlds[0][lane] = Qb[(size_t)pA * gC + lane];
    qlds[1][lane] = Qb[(size_t)(pA + 1) * gC + lane];
    __syncthreads();

    int j = idxi[(size_t)p * gK + kk];
    const float* xp = xyz + (size_t)p * 3;
    const float* xj = xyz + ((size_t)b * gN + j) * 3;
    float dx = xp[0] - xj[0];
    float dy = xp[1] - xj[1];
    float dz = xp[2] - xj[2];

    float acc[64];   // matmul accumulator (register, as in R14)
    float pe[64];    // positional encoding (register, replaces peb LDS)

    // ---- fc_delta layer 1 ----
#pragma unroll
    for (int c = 0; c < 64; ++c)
        acc[c] = dx * dW1[c] + dy * dW1[64 + c] + dz * dW1[128 + c] + db1[c];

    // ---- LN (in-lane) + relu -> actb ----
    {
        float s0 = 0, s1 = 0, s2 = 0, s3 = 0;
#pragma unroll
        for (int c = 0; c < 64; c += 4) { s0 += acc[c]; s1 += acc[c + 1]; s2 += acc[c + 2]; s3 += acc[c + 3]; }
        float mu = ((s0 + s1) + (s2 + s3)) * (1.f / 64);
        float v0 = 0, v1 = 0, v2 = 0, v3 = 0;
#pragma unroll
        for (int c = 0; c < 64; c += 4) {
            acc[c] -= mu; acc[c + 1] -= mu; acc[c + 2] -= mu; acc[c + 3] -= mu;
            v0 += acc[c] * acc[c]; v1 += acc[c + 1] * acc[c + 1];
            v2 += acc[c + 2] * acc[c + 2]; v3 += acc[c + 3] * acc[c + 3];
        }
        float var = ((v0 + v1) + (v2 + v3)) * (1.f / 64);
        float inv = 1.f / sqrtf(var + 1e-5f);
#pragma unroll
        for (int c = 0; c < 64; ++c)
            actb[c][lane] = fmaxf(acc[c] * inv * dgv[c] + dbv[c], 0.f);
    }

    // ---- fc_delta layer 2: pe = h1 @ dW2 + db2 (accumulate in regs) ----
#pragma unroll
    for (int c = 0; c < 64; ++c) pe[c] = db2[c];
    for (int cp = 0; cp < 64; ++cp) {
        float h = actb[cp][lane];
#pragma unroll
        for (int c = 0; c < 64; ++c) pe[c] += h * dW2[cp * 64 + c];
    }

    // ---- attn_in = (q - k) + pe -> actb ----
    {
        const float* Kj = Kb + ((size_t)b * gN + j) * gC;
#pragma unroll
        for (int c4 = 0; c4 < 16; ++c4) {
            float4 kv = reinterpret_cast<const float4*>(Kj)[c4];
            int c = c4 * 4;
            actb[c + 0][lane] = (qlds[half][c + 0] - kv.x) + pe[c + 0];
            actb[c + 1][lane] = (qlds[half][c + 1] - kv.y) + pe[c + 1];
            actb[c + 2][lane] = (qlds[half][c + 2] - kv.z) + pe[c + 2];
            actb[c + 3][lane] = (qlds[half][c + 3] - kv.w) + pe[c + 3];
        }
    }

    // ---- fc_gamma layer 1 ----
#pragma unroll
    for (int c = 0; c < 64; ++c) acc[c] = gb1[c];
    for (int cp = 0; cp < 64; ++cp) {
        float h = actb[cp][lane];
#pragma unroll
        for (int c = 0; c < 64; ++c) acc[c] += h * gW1[cp * 64 + c];
    }
    // ---- LN + relu -> actb ----
    {
        float s0 = 0, s1 = 0, s2 = 0, s3 = 0;
#pragma unroll
        for (int c = 0; c < 64; c += 4) { s0 += acc[c]; s1 += acc[c + 1]; s2 += acc[c + 2]; s3 += acc[c + 3]; }
        float mu = ((s0 + s1) + (s2 + s3)) * (1.f / 64);
        float v0 = 0, v1 = 0, v2 = 0, v3 = 0;
#pragma unroll
        for (int c = 0; c < 64; c += 4) {
            acc[c] -= mu; acc[c + 1] -= mu; acc[c + 2] -= mu; acc[c + 3] -= mu;
            v0 += acc[c] * acc[c]; v1 += acc[c + 1] * acc[c + 1];
            v2 += acc[c + 2] * acc[c + 2]; v3 += acc[c + 3] * acc[c + 3];
        }
        float var = ((v0 + v1) + (v2 + v3)) * (1.f / 64);
        float inv = 1.f / sqrtf(var + 1e-5f);
#pragma unroll
        for (int c = 0; c < 64; ++c)
            actb[c][lane] = fmaxf(acc[c] * inv * ggv[c] + gbv[c], 0.f);
    }

    // ---- fc_gamma layer 2 -> logits in acc ----
#pragma unroll
    for (int c = 0; c < 64; ++c) acc[c] = gb2[c];
    for (int cp = 0; cp < 64; ++cp) {
        float h = actb[cp][lane];
#pragma unroll
        for (int c = 0; c < 64; ++c) acc[c] += h * gW2[cp * 64 + c];
    }
#pragma unroll
    for (int c = 0; c < 64; ++c)
        acc[c] = acc[c] * 0.3535533905932738f;   // /sqrt(8)

    // ---- per-channel softmax over k (half-wave) + out = sum a*(v+pe) ----
    {
        const float* Vj = Vb + ((size_t)b * gN + j) * gC;
        float* op = att + (size_t)p * gC;
        for (int c4 = 0; c4 < 16; ++c4) {
            float4 vv4 = reinterpret_cast<const float4*>(Vj)[c4];
            float vva[4] = {vv4.x, vv4.y, vv4.z, vv4.w};
#pragma unroll
            for (int i = 0; i < 4; ++i) {
                int c = c4 * 4 + i;
                float l = acc[c];
                float gm = l;
#pragma unroll
                for (int m = 16; m; m >>= 1) gm = fmaxf(gm, __shfl_xor(gm, m, 64));
                float e = expf(l - gm);
                float w = e * (vva[i] + pe[c]);
                float se = e, sw = w;
#pragma unroll
                for (int m = 16; m; m >>= 1) {
                    se += __shfl_xor(se, m, 64);
                    sw += __shfl_xor(sw, m, 64);
                }
                if (kk == (c & 31)) op[c] = sw / se;
            }
        }
    }
}

// =====================================================================
// D: out2 = LN2(att @ Wo + bo) in place; accumulate channel mean. (unchanged)
// =====================================================================
__global__ __launch_bounds__(256) void k_out(
    float* __restrict__ att,
    const float* __restrict__ Wo, const float* __restrict__ bo,
    const float* __restrict__ ln2g, const float* __restrict__ ln2b,
    float* __restrict__ meanb)
{
    __shared__ __align__(16) float hb[4][64];
    int lane = threadIdx.x & 63;
    int p = blockIdx.x * 4 + (threadIdx.x >> 6);
    int b = p >> 13;
    float* hbuf = hb[threadIdx.x >> 6];
    float wo[64];
#pragma unroll
    for (int r = 0; r < 64; ++r) wo[r] = Wo[r * 64 + lane];
    float x = att[(size_t)p * gC + lane];
    hbuf[lane] = x;
    float acc = bo[lane];
#pragma unroll
    for (int q4 = 0; q4 < 16; ++q4) {
        float4 hq = *reinterpret_cast<const float4*>(&hbuf[q4 * 4]);
        acc += hq.x * wo[q4 * 4 + 0] + hq.y * wo[q4 * 4 + 1]
             + hq.z * wo[q4 * 4 + 2] + hq.w * wo[q4 * 4 + 3];
    }
    float mu = wsum(acc) * (1.f / 64);
    float d = acc - mu;
    float var = wsum(d * d) * (1.f / 64);
    float inv = 1.f / sqrtf(var + 1e-5f);
    float y = d * inv * ln2g[lane] + ln2b[lane];
    att[(size_t)p * gC + lane] = y;
    atomicAdd(&meanb[b * 64 + lane], y * (1.f / gN));
}

// =====================================================================
// E: cw = sigmoid(relu(mean @ ca_W1 + ca_b1) @ ca_W2 + ca_b2) (unchanged)
// =====================================================================
__global__ void k_cw(const float* __restrict__ meanb,
                     const float* __restrict__ caW1, const float* __restrict__ cab1,
                     const float* __restrict__ caW2, const float* __restrict__ cab2,
                     float* __restrict__ cw)
{
    int b = blockIdx.x, lane = threadIdx.x;    // 64 threads
    float mv = meanb[b * 64 + lane];
    float hj = (lane < 16) ? cab1[lane] : 0.f;
    for (int cp = 0; cp < 64; ++cp) {
        float mcp = __shfl(mv, cp, 64);
        if (lane < 16) hj += mcp * caW1[cp * 16 + lane];
    }
    hj = fmaxf(hj, 0.f);
    float acc = cab2[lane];
    for (int jj = 0; jj < 16; ++jj) {
        float hv = __shfl(hj, jj, 64);
        acc += hv * caW2[jj * 64 + lane];
    }
    cw[b * 64 + lane] = 1.f / (1.f + expf(-acc));
}

// =====================================================================
// F: out = LN3(out2 * cw) + features  -> fp32 (unchanged)
// =====================================================================
__global__ __launch_bounds__(256) void k_final(
    const float* __restrict__ out2, const float* __restrict__ cw,
    const float* __restrict__ ln3g, const float* __restrict__ ln3b,
    const float* __restrict__ feat, float* __restrict__ outp)
{
    int lane = threadIdx.x & 63;
    int p = blockIdx.x * 4 + (threadIdx.x >> 6);
    int b = p >> 13;
    float x = out2[(size_t)p * gC + lane] * cw[b * 64 + lane];
    float mu = wsum(x) * (1.f / 64);
    float d = x - mu;
    float var = wsum(d * d) * (1.f / 64);
    float inv = 1.f / sqrtf(var + 1e-5f);
    float y = d * inv * ln3g[lane] + ln3b[lane];
    outp[(size_t)p * gC + lane] = y + feat[(size_t)p * gC + lane];
}

// =====================================================================
extern "C" void kernel_launch(void* const* d_in, const int* in_sizes, int n_in,
                              void* d_out, int out_size, void* d_ws, size_t ws_size,
                              hipStream_t stream)
{
    (void)in_sizes; (void)n_in; (void)out_size; (void)ws_size;
    const float* xyz  = (const float*)d_in[0];
    const float* feat = (const float*)d_in[1];
    const float* ln1g = (const float*)d_in[2];
    const float* ln1b = (const float*)d_in[3];
    const float* Wq   = (const float*)d_in[4];
    const float* bq   = (const float*)d_in[5];
    const float* Wk   = (const float*)d_in[6];
    const float* bk   = (const float*)d_in[7];
    const float* Wv   = (const float*)d_in[8];
    const float* bv   = (const float*)d_in[9];
    const float* dW1  = (const float*)d_in[10];
    const float* db1  = (const float*)d_in[11];
    const float* dg   = (const float*)d_in[12];
    const float* db   = (const float*)d_in[13];
    const float* dW2  = (const float*)d_in[14];
    const float* db2  = (const float*)d_in[15];
    const float* gW1  = (const float*)d_in[16];
    const float* gb1  = (const float*)d_in[17];
    const float* gg   = (const float*)d_in[18];
    const float* gb   = (const float*)d_in[19];
    const float* gW2  = (const float*)d_in[20];
    const float* gb2  = (const float*)d_in[21];
    const float* Wo   = (const float*)d_in[22];
    const float* bo   = (const float*)d_in[23];
    const float* ln2g = (const float*)d_in[24];
    const float* ln2b = (const float*)d_in[25];
    const float* caW1 = (const float*)d_in[26];
    const float* cab1 = (const float*)d_in[27];
    const float* caW2 = (const float*)d_in[28];
    const float* cab2 = (const float*)d_in[29];
    const float* ln3g = (const float*)d_in[30];
    const float* ln3b = (const float*)d_in[31];

    const size_t BNC = (size_t)gB * gN * gC;      // 1,048,576
    float* Q    = (float*)d_ws;
    float* Kt   = Q + BNC;
    float* Vt   = Kt + BNC;
    float* att  = Vt + BNC;                        // reused in-place as out2
    int*   idx  = (int*)(att + BNC);
    float* meanb = (float*)(idx + (size_t)gB * gN * gK);
    float* cw    = meanb + 128;

    const int PB = (gB * gN) / 4;                  // 4096 blocks, wave-per-point

    k_lnqkv<<<PB, 256, 0, stream>>>(feat, ln1g, ln1b, Wq, bq, Wk, bk, Wv, bv, Q, Kt, Vt, meanb);
    k_knn<<<gB * gN, 64, 0, stream>>>(xyz, idx);
    k_attn<<<(gB * gN) / 2, 64, 0, stream>>>(xyz, Q, Kt, Vt, idx,
                                             dW1, db1, dg, db, dW2, db2,
                                             gW1, gb1, gg, gb, gW2, gb2, att);
    k_out<<<PB, 256, 0, stream>>>(att, Wo, bo, ln2g, ln2b, meanb);
    k_cw<<<gB, 64, 0, stream>>>(meanb, caW1, cab1, caW2, cab2, cw);
    k_final<<<PB, 256, 0, stream>>>(att, cw, ln3g, ln3b, feat, (float*)d_out);
}